// Round 9
// baseline (48.707 us; speedup 1.0000x reference)
//
#include <hip/hip_runtime.h>

// Problem constants (fixed by the reference)
#define NXY   16
#define NZ    8
#define NS    2048      // states = 16*16*8
#define NT    2048      // tokens
#define NB    16        // stories
#define NL    16        // story length
#define NSENT 16        // tokens per sentence
#define NEGV  (-1e9f)

// ---------------------------------------------------------------------------
// K1 v2: fused smoothing + transpose, register x-pass (round-6 proven body).
// ---------------------------------------------------------------------------
#define TT   16
#define SPAD 17

__global__ __launch_bounds__(256) void k_smooth(const float* __restrict__ em,
                                                float* __restrict__ emT) {
    __shared__ float S[256 * SPAD];   // 17408 B
    const int tid = threadIdx.x;
    const int t0 = blockIdx.x * TT;
    const int z = blockIdx.y;
    const int toff = tid & 15, y = tid >> 4;

    const float* base = em + ((size_t)z * 256 + y * 16) * NT + t0 + toff;
    float ex[16];
#pragma unroll
    for (int x = 0; x < 16; ++x)
        ex[x] = __expf(base[(size_t)x * NT]);

#pragma unroll
    for (int x = 0; x < 16; ++x) {
        const int xm2 = x - 2 < 0 ? 0 : x - 2, xm1 = x - 1 < 0 ? 0 : x - 1;
        const int xp1 = x + 1 > 15 ? 15 : x + 1, xp2 = x + 2 > 15 ? 15 : x + 2;
        S[(y * 16 + x) * SPAD + toff] = ex[xm2] + ex[xm1] + ex[x] + ex[xp1] + ex[xp2];
    }
    __syncthreads();

    const int x2 = tid & 15, y2 = tid >> 4;
    int ry[5];
#pragma unroll
    for (int k = 0; k < 5; ++k) {
        int yy = y2 + k - 2; yy = yy < 0 ? 0 : (yy > 15 ? 15 : yy);
        ry[k] = (yy * 16 + x2) * SPAD;
    }
    const float LOG25 = 3.2188758248682006f;   // log(5)+log(5)
    float* ob = emT + (size_t)t0 * NS + z * 256 + tid;
#pragma unroll
    for (int t = 0; t < TT; ++t) {
        float a = S[ry[0] + t] + S[ry[1] + t] + S[ry[2] + t] + S[ry[3] + t] + S[ry[4] + t];
        ob[(size_t)t * NS] = __logf(a) - LOG25;
    }
}

// ---------------------------------------------------------------------------
// K2: e_all[b,l,s] = sum_j em_T[tok[b,l,j], s]   (round-2 proven, unchanged)
// ---------------------------------------------------------------------------
__global__ __launch_bounds__(256) void k_eall(const int* __restrict__ stories,
                                              const float* __restrict__ emT,
                                              float* __restrict__ eall) {
    const int bl = blockIdx.x;
    const int col = blockIdx.y * 256 + threadIdx.x;
    __shared__ int toks[NSENT];
    if (threadIdx.x < NSENT) toks[threadIdx.x] = stories[bl * NSENT + threadIdx.x];
    __syncthreads();

    float4 a = make_float4(0.f, 0.f, 0.f, 0.f);
#pragma unroll 4
    for (int j = 0; j < NSENT; ++j) {
        float4 v = ((const float4*)(emT + (size_t)toks[j] * NS))[col];
        a.x += v.x; a.y += v.y; a.z += v.z; a.w += v.w;
    }
    ((float4*)(eall + (size_t)bl * NS))[col] = a;
}

// ---------------------------------------------------------------------------
// K3 v3: forward recursion with a GLOBAL-MEMORY-FREE steady-state loop.
// One block/story, 1024 threads, thread owns even/odd state pair (2t, 2t+1).
//   - ALL e rows preloaded to registers before the loop (15 x float2).
//   - ALL step results kept in registers (16 x float2), stored after the loop.
//   - loop body: 7 vectorized LDS reads + VALU/trans + 1 ds_write + barrier.
//     No vmem in flight -> the compiler's pre-barrier vmcnt(0) is free
//     (round-8 lesson: deferred stores still get drained by the barrier).
//   - guard-padded prev/cur buffers (front 16, back 512, zeroed once): no
//     index clamping; pad reads return 0.0, killed by finite NEGV weights.
// ---------------------------------------------------------------------------
#define FPAD_F 16
#define FPAD_B 512

__global__ __launch_bounds__(1024) void k_forward(const float* __restrict__ trans,
                                                  const float* __restrict__ priors,
                                                  const float* __restrict__ eall,
                                                  float* __restrict__ out) {
    __shared__ float rawA[FPAD_F + NS + FPAD_B];   // 10.3 KB each
    __shared__ float rawB[FPAD_F + NS + FPAD_B];
    float* A = rawA + FPAD_F;
    float* Bv = rawB + FPAD_F;

    const int b = blockIdx.x;
    const int tid = threadIdx.x;
    const int h0 = tid * 2;                        // even state; h1 = h0+1

    // zero the guard pads (finite junk; NEGV weights kill their contribution)
    for (int i = tid; i < FPAD_F + FPAD_B; i += 1024) {
        int idx = (i < FPAD_F) ? i : FPAD_F + NS + (i - FPAD_F);
        rawA[idx] = 0.f;
        rawB[idx] = 0.f;
    }

    // gather the <=7 incoming weights for both states (registers, fixed)
    float w0[7], w1[7];
    {
        const int x = h0 & 15, y = (h0 >> 4) & 15, z = h0 >> 8;    // x even
        const float* row = trans + (size_t)h0 * NS;
        w0[0] = row[h0];
        w0[1] = row[h0 + 1];                        // x<15 always (x even)
        w0[2] = (x > 0)  ? row[h0 - 1]   : NEGV;
        w0[3] = (y < 15) ? row[h0 + 16]  : NEGV;
        w0[4] = (y > 0)  ? row[h0 - 16]  : NEGV;
        w0[5] = (z < 7)  ? row[h0 + 256] : NEGV;
        w0[6] = (z < 6)  ? row[h0 + 512] : NEGV;
    }
    {
        const int h1 = h0 + 1;
        const int x = h1 & 15, y = (h1 >> 4) & 15, z = h1 >> 8;    // x odd >=1
        const float* row = trans + (size_t)h1 * NS;
        w1[0] = row[h1];
        w1[1] = (x < 15) ? row[h1 + 1]   : NEGV;
        w1[2] = row[h1 - 1];                        // x>0 always (x odd)
        w1[3] = (y < 15) ? row[h1 + 16]  : NEGV;
        w1[4] = (y > 0)  ? row[h1 - 16]  : NEGV;
        w1[5] = (z < 7)  ? row[h1 + 256] : NEGV;
        w1[6] = (z < 6)  ? row[h1 + 512] : NEGV;
    }

    const float* eb = eall + (size_t)b * NL * NS;

    // preload ALL emission pairs (static-indexed register array)
    float2 er[NL];
#pragma unroll
    for (int l = 1; l < NL; ++l)
        er[l] = *(const float2*)(eb + (size_t)l * NS + h0);
    float2 e0 = *(const float2*)(eb + h0);
    float2 pr = *(const float2*)(priors + h0);

    float2 res[NL];                                // all results in registers
    res[0] = make_float2(e0.x + pr.x, e0.y + pr.y);
    *(float2*)(A + h0) = res[0];
    __syncthreads();                               // drains all preloads once

#pragma unroll
    for (int l = 1; l < NL; ++l) {
        float* prev = (l & 1) ? A : Bv;
        float* cur  = (l & 1) ? Bv : A;

        // 7 vectorized LDS reads cover both states' 7-neighbor sets
        float2 c0 = *(const float2*)(prev + h0);          // prev[h0], prev[h0+1]
        float  xl = prev[h0 - 1];
        float  xr = prev[h0 + 2];
        float2 ym = *(const float2*)(prev + h0 - 16);
        float2 yp = *(const float2*)(prev + h0 + 16);
        float2 z1 = *(const float2*)(prev + h0 + 256);
        float2 z2 = *(const float2*)(prev + h0 + 512);

        // state h0: self=c0.x, x+1=c0.y, x-1=xl, y+-16, z+256, z+512
        float a0 = w0[0] + c0.x, a1 = w0[1] + c0.y, a2 = w0[2] + xl;
        float a3 = w0[3] + yp.x, a4 = w0[4] + ym.x, a5 = w0[5] + z1.x, a6 = w0[6] + z2.x;
        float m0 = fmaxf(fmaxf(fmaxf(a0, a1), fmaxf(a2, a3)),
                         fmaxf(fmaxf(a4, a5), a6));
        float s0 = __expf(a0 - m0) + __expf(a1 - m0) + __expf(a2 - m0) + __expf(a3 - m0) +
                   __expf(a4 - m0) + __expf(a5 - m0) + __expf(a6 - m0);
        // state h1: self=c0.y, x+1=xr, x-1=c0.x
        float b0 = w1[0] + c0.y, b1 = w1[1] + xr, b2 = w1[2] + c0.x;
        float b3 = w1[3] + yp.y, b4 = w1[4] + ym.y, b5 = w1[5] + z1.y, b6 = w1[6] + z2.y;
        float m1 = fmaxf(fmaxf(fmaxf(b0, b1), fmaxf(b2, b3)),
                         fmaxf(fmaxf(b4, b5), b6));
        float s1 = __expf(b0 - m1) + __expf(b1 - m1) + __expf(b2 - m1) + __expf(b3 - m1) +
                   __expf(b4 - m1) + __expf(b5 - m1) + __expf(b6 - m1);

        res[l] = make_float2(er[l].x + m0 + __logf(s0), er[l].y + m1 + __logf(s1));

        if (l < NL - 1) {                          // last step feeds nothing
            *(float2*)(cur + h0) = res[l];
            __syncthreads();
        }
    }

    // write the whole output block, fully coalesced
#pragma unroll
    for (int l = 0; l < NL; ++l)
        *(float2*)(out + ((size_t)l * NB + b) * NS + h0) = res[l];
}

// ---------------------------------------------------------------------------
extern "C" void kernel_launch(void* const* d_in, const int* in_sizes, int n_in,
                              void* d_out, int out_size, void* d_ws, size_t ws_size,
                              hipStream_t stream) {
    (void)in_sizes; (void)n_in; (void)out_size; (void)ws_size;
    const int* stories  = (const int*)d_in[0];
    // d_in[1] = story_length (== NL), unused
    const float* priors = (const float*)d_in[2];
    const float* trans  = (const float*)d_in[3];
    const float* em     = (const float*)d_in[4];
    float* out = (float*)d_out;

    float* emT  = (float*)d_ws;                    // [NT][NS]   16 MB
    float* eall = emT + (size_t)NT * NS;           // [NB*NL][NS] 2 MB

    k_smooth<<<dim3(NT / TT, NZ), 256, 0, stream>>>(em, emT);
    k_eall<<<dim3(NB * NL, 2), 256, 0, stream>>>(stories, emT, eall);
    k_forward<<<dim3(NB), 1024, 0, stream>>>(trans, priors, eall, out);
}

// Round 10
// 42.106 us; speedup vs baseline: 1.1568x; 1.1568x over previous
//
#include <hip/hip_runtime.h>

// Problem constants (fixed by the reference)
#define NXY   16
#define NZ    8
#define NS    2048      // states = 16*16*8
#define NT    2048      // tokens
#define NB    16        // stories
#define NL    16        // story length
#define NSENT 16        // tokens per sentence
#define NEGV  (-1e9f)

// ---------------------------------------------------------------------------
// K0: weight-table prep. One thread per (neighbor-slot, state): the scattered
// trans gather is done ONCE with full-chip TLP instead of 16x redundantly at
// 6% occupancy inside k_forward (round-9 lesson: that gather was ~30us and
// dominated the whole pipeline). Output wtab[k][h], h-contiguous -> k_forward
// reads it as 7 coalesced float2 loads per thread.
// ---------------------------------------------------------------------------
__global__ __launch_bounds__(256) void k_prep(const float* __restrict__ trans,
                                              float* __restrict__ wtab) {
    const int g = blockIdx.x * 256 + threadIdx.x;      // [0, 7*NS)
    if (g >= 7 * NS) return;
    const int k = g >> 11;           // neighbor slot 0..6
    const int h = g & (NS - 1);      // state
    const int x = h & 15, y = (h >> 4) & 15, z = h >> 8;
    const float* row = trans + (size_t)h * NS;
    float w;
    switch (k) {
        case 0: w = row[h]; break;
        case 1: w = (x < 15) ? row[h + 1]   : NEGV; break;
        case 2: w = (x > 0)  ? row[h - 1]   : NEGV; break;
        case 3: w = (y < 15) ? row[h + 16]  : NEGV; break;
        case 4: w = (y > 0)  ? row[h - 16]  : NEGV; break;
        case 5: w = (z < 7)  ? row[h + 256] : NEGV; break;
        default: w = (z < 6) ? row[h + 512] : NEGV; break;
    }
    wtab[g] = w;
}

// ---------------------------------------------------------------------------
// K1 v2: fused smoothing + transpose, register x-pass (round-6 proven body).
// ---------------------------------------------------------------------------
#define TT   16
#define SPAD 17

__global__ __launch_bounds__(256) void k_smooth(const float* __restrict__ em,
                                                float* __restrict__ emT) {
    __shared__ float S[256 * SPAD];   // 17408 B
    const int tid = threadIdx.x;
    const int t0 = blockIdx.x * TT;
    const int z = blockIdx.y;
    const int toff = tid & 15, y = tid >> 4;

    const float* base = em + ((size_t)z * 256 + y * 16) * NT + t0 + toff;
    float ex[16];
#pragma unroll
    for (int x = 0; x < 16; ++x)
        ex[x] = __expf(base[(size_t)x * NT]);

#pragma unroll
    for (int x = 0; x < 16; ++x) {
        const int xm2 = x - 2 < 0 ? 0 : x - 2, xm1 = x - 1 < 0 ? 0 : x - 1;
        const int xp1 = x + 1 > 15 ? 15 : x + 1, xp2 = x + 2 > 15 ? 15 : x + 2;
        S[(y * 16 + x) * SPAD + toff] = ex[xm2] + ex[xm1] + ex[x] + ex[xp1] + ex[xp2];
    }
    __syncthreads();

    const int x2 = tid & 15, y2 = tid >> 4;
    int ry[5];
#pragma unroll
    for (int k = 0; k < 5; ++k) {
        int yy = y2 + k - 2; yy = yy < 0 ? 0 : (yy > 15 ? 15 : yy);
        ry[k] = (yy * 16 + x2) * SPAD;
    }
    const float LOG25 = 3.2188758248682006f;   // log(5)+log(5)
    float* ob = emT + (size_t)t0 * NS + z * 256 + tid;
#pragma unroll
    for (int t = 0; t < TT; ++t) {
        float a = S[ry[0] + t] + S[ry[1] + t] + S[ry[2] + t] + S[ry[3] + t] + S[ry[4] + t];
        ob[(size_t)t * NS] = __logf(a) - LOG25;
    }
}

// ---------------------------------------------------------------------------
// K2: e_all[b,l,s] = sum_j em_T[tok[b,l,j], s]   (round-2 proven, unchanged)
// ---------------------------------------------------------------------------
__global__ __launch_bounds__(256) void k_eall(const int* __restrict__ stories,
                                              const float* __restrict__ emT,
                                              float* __restrict__ eall) {
    const int bl = blockIdx.x;
    const int col = blockIdx.y * 256 + threadIdx.x;
    __shared__ int toks[NSENT];
    if (threadIdx.x < NSENT) toks[threadIdx.x] = stories[bl * NSENT + threadIdx.x];
    __syncthreads();

    float4 a = make_float4(0.f, 0.f, 0.f, 0.f);
#pragma unroll 4
    for (int j = 0; j < NSENT; ++j) {
        float4 v = ((const float4*)(emT + (size_t)toks[j] * NS))[col];
        a.x += v.x; a.y += v.y; a.z += v.z; a.w += v.w;
    }
    ((float4*)(eall + (size_t)bl * NS))[col] = a;
}

// ---------------------------------------------------------------------------
// K3 v4: forward recursion (round-8 passing body, small register footprint)
// with weights from the compact wtab (7 coalesced float2 loads, L2-hot 57KB)
// instead of the 300KB/block scattered trans gather.
// ---------------------------------------------------------------------------
#define FPAD_F 16
#define FPAD_B 512

__global__ __launch_bounds__(1024) void k_forward(const float* __restrict__ wtab,
                                                  const float* __restrict__ priors,
                                                  const float* __restrict__ eall,
                                                  float* __restrict__ out) {
    __shared__ float rawA[FPAD_F + NS + FPAD_B];   // 10.3 KB each
    __shared__ float rawB[FPAD_F + NS + FPAD_B];
    float* A = rawA + FPAD_F;
    float* Bv = rawB + FPAD_F;

    const int b = blockIdx.x;
    const int tid = threadIdx.x;
    const int h0 = tid * 2;                        // even state; h1 = h0+1

    // zero the guard pads (finite junk; NEGV weights kill their contribution)
    for (int i = tid; i < FPAD_F + FPAD_B; i += 1024) {
        int idx = (i < FPAD_F) ? i : FPAD_F + NS + (i - FPAD_F);
        rawA[idx] = 0.f;
        rawB[idx] = 0.f;
    }

    // weights for the state pair: w[k].x -> state h0, w[k].y -> state h1
    float2 w[7];
#pragma unroll
    for (int k = 0; k < 7; ++k)
        w[k] = *(const float2*)(wtab + (size_t)k * NS + h0);

    const float* eb = eall + (size_t)b * NL * NS;
    float2 e0 = *(const float2*)(eb + h0);
    float2 pr = *(const float2*)(priors + h0);
    float2 vres = make_float2(e0.x + pr.x, e0.y + pr.y);
    *(float2*)(A + h0) = vres;
    float2 e_cur = *(const float2*)(eb + NS + h0);   // e for l=1
    __syncthreads();

    float* prev = A;
    float* cur = Bv;
    for (int l = 1; l < NL; ++l) {
        // deferred store of step l-1's result
        *(float2*)(out + ((size_t)(l - 1) * NB + b) * NS + h0) = vres;
        // prefetch next step's e pair
        float2 e_nxt = make_float2(0.f, 0.f);
        if (l + 1 < NL) e_nxt = *(const float2*)(eb + (size_t)(l + 1) * NS + h0);

        // 7 vectorized LDS reads cover both states' 7-neighbor sets
        float2 c0 = *(const float2*)(prev + h0);          // prev[h0], prev[h0+1]
        float  xl = prev[h0 - 1];
        float  xr = prev[h0 + 2];
        float2 ym = *(const float2*)(prev + h0 - 16);
        float2 yp = *(const float2*)(prev + h0 + 16);
        float2 z1 = *(const float2*)(prev + h0 + 256);
        float2 z2 = *(const float2*)(prev + h0 + 512);

        // state h0: self=c0.x, x+1=c0.y, x-1=xl, y+-16, z+256, z+512
        float a0 = w[0].x + c0.x, a1 = w[1].x + c0.y, a2 = w[2].x + xl;
        float a3 = w[3].x + yp.x, a4 = w[4].x + ym.x, a5 = w[5].x + z1.x, a6 = w[6].x + z2.x;
        float m0 = fmaxf(fmaxf(fmaxf(a0, a1), fmaxf(a2, a3)),
                         fmaxf(fmaxf(a4, a5), a6));
        float s0 = __expf(a0 - m0) + __expf(a1 - m0) + __expf(a2 - m0) + __expf(a3 - m0) +
                   __expf(a4 - m0) + __expf(a5 - m0) + __expf(a6 - m0);
        // state h1: self=c0.y, x+1=xr, x-1=c0.x
        float b0 = w[0].y + c0.y, b1 = w[1].y + xr, b2 = w[2].y + c0.x;
        float b3 = w[3].y + yp.y, b4 = w[4].y + ym.y, b5 = w[5].y + z1.y, b6 = w[6].y + z2.y;
        float m1 = fmaxf(fmaxf(fmaxf(b0, b1), fmaxf(b2, b3)),
                         fmaxf(fmaxf(b4, b5), b6));
        float s1 = __expf(b0 - m1) + __expf(b1 - m1) + __expf(b2 - m1) + __expf(b3 - m1) +
                   __expf(b4 - m1) + __expf(b5 - m1) + __expf(b6 - m1);

        vres = make_float2(e_cur.x + m0 + __logf(s0), e_cur.y + m1 + __logf(s1));
        *(float2*)(cur + h0) = vres;
        __syncthreads();

        e_cur = e_nxt;
        float* tmp = prev; prev = cur; cur = tmp;
    }

    // final step's result
    *(float2*)(out + ((size_t)(NL - 1) * NB + b) * NS + h0) = vres;
}

// ---------------------------------------------------------------------------
extern "C" void kernel_launch(void* const* d_in, const int* in_sizes, int n_in,
                              void* d_out, int out_size, void* d_ws, size_t ws_size,
                              hipStream_t stream) {
    (void)in_sizes; (void)n_in; (void)out_size; (void)ws_size;
    const int* stories  = (const int*)d_in[0];
    // d_in[1] = story_length (== NL), unused
    const float* priors = (const float*)d_in[2];
    const float* trans  = (const float*)d_in[3];
    const float* em     = (const float*)d_in[4];
    float* out = (float*)d_out;

    float* emT  = (float*)d_ws;                    // [NT][NS]    16 MB
    float* eall = emT + (size_t)NT * NS;           // [NB*NL][NS]  2 MB
    float* wtab = eall + (size_t)NB * NL * NS;     // [7][NS]     57 KB

    k_prep<<<dim3((7 * NS + 255) / 256), 256, 0, stream>>>(trans, wtab);
    k_smooth<<<dim3(NT / TT, NZ), 256, 0, stream>>>(em, emT);
    k_eall<<<dim3(NB * NL, 2), 256, 0, stream>>>(stories, emT, eall);
    k_forward<<<dim3(NB), 1024, 0, stream>>>(wtab, priors, eall, out);
}